// Round 20
// baseline (301.127 us; speedup 1.0000x reference)
//
#include <hip/hip_runtime.h>
#include <hip/hip_bf16.h>
#include <stdint.h>
#include <math.h>

#define DEV static __device__ __forceinline__

typedef short bf16x8 __attribute__((ext_vector_type(8)));
typedef float f32x4 __attribute__((ext_vector_type(4)));
typedef float f32x16 __attribute__((ext_vector_type(16)));
typedef unsigned short u16;

static constexpr int Sq   = 1024;
static constexpr int Dm   = 1024;
static constexpr int Hh   = 16;
static constexpr int Mrows = 4096; // B*S
static constexpr int DFFn = 4096;

// ---------- helpers ----------

DEV u16 f2bf(float f) {  // fp32 -> bf16 (RNE)
    union { float f; unsigned u; } c; c.f = f;
    unsigned u = c.u;
    return (u16)((u + 0x7FFFu + ((u >> 16) & 1u)) >> 16);
}

DEV float bf2f(u16 v) {
    union { unsigned u; float f; } c; c.u = ((unsigned)v) << 16; return c.f;
}

DEV unsigned cvt_pk_bf16(float lo, float hi) {  // D[15:0]=bf16(lo), D[31:16]=bf16(hi)
    unsigned r;
    asm("v_cvt_pk_bf16_f32 %0, %1, %2" : "=v"(r) : "v"(lo), "v"(hi));
    return r;
}

DEV float fast_exp2(float x) {   // raw v_exp_f32, no libm range fixup
#if __has_builtin(__builtin_amdgcn_exp2f)
    return __builtin_amdgcn_exp2f(x);
#else
    float r; asm("v_exp_f32 %0, %1" : "=v"(r) : "v"(x)); return r;
#endif
}

DEV void gload_lds16(void* lds, const void* g) {
    using gvp = __attribute__((address_space(1))) void*;
    using lvp = __attribute__((address_space(3))) void*;
    __builtin_amdgcn_global_load_lds((gvp)const_cast<void*>(g), (lvp)lds, 16, 0, 0);
}

// line-pair swizzle: XOR byte bits 4-6 with (L>>7)&7. Involution, 16B-granular.
DEV int swz64(int L) { return L ^ (((L >> 7) & 7) << 4); }

// ---------- batched fp32 -> bf16 cast (10 segments, one launch) ----------

__global__ __launch_bounds__(256) void cast_multi_kernel(
    const float* s0, const float* s1, const float* s2, const float* s3, const float* s4,
    const float* s5, const float* s6, const float* s7, const float* s8, const float* s9,
    u16* d0, u16* d1, u16* d2, u16* d3, u16* d4,
    u16* d5, u16* d6, u16* d7, u16* d8, u16* d9,
    int e0, int e1, int e2, int e3, int e4,
    int e5, int e6, int e7, int e8, int e9)
{
    int i = blockIdx.x * 256 + threadIdx.x;   // float4 index
    if (i >= e9) return;
    const float* s; u16* d; int b;
    if      (i < e0) { s = s0; d = d0; b = 0;  }
    else if (i < e1) { s = s1; d = d1; b = e0; }
    else if (i < e2) { s = s2; d = d2; b = e1; }
    else if (i < e3) { s = s3; d = d3; b = e2; }
    else if (i < e4) { s = s4; d = d4; b = e3; }
    else if (i < e5) { s = s5; d = d5; b = e4; }
    else if (i < e6) { s = s6; d = d6; b = e5; }
    else if (i < e7) { s = s7; d = d7; b = e6; }
    else if (i < e8) { s = s8; d = d8; b = e7; }
    else             { s = s9; d = d9; b = e8; }
    int j = i - b;
    float4 v = ((const float4*)s)[j];
    ushort4 o;
    o.x = f2bf(v.x); o.y = f2bf(v.y); o.z = f2bf(v.z); o.w = f2bf(v.w);
    ((ushort4*)d)[j] = o;
}

// ---------- shared 8-phase K-loop body (R18 waits = best measured) ----------
// R20: coalesced epilogue via LDS bounce. After the K-loop (one barrier; last-iter
// vmcnt(0) already drained all staging), the 128KB LDS is dead -> write the bf16
// output tile into LDS with an XOR row-swizzle (kills the 8-way row-stride bank
// conflict), barrier, then 16 passes of fully-coalesced 16B stores (half-wave =
// 512B contiguous). Replaces 128 scattered global_store_short per thread.

template<typename XF>
DEV void g256_body(const u16* A, const u16* W, size_t tm, size_t tn, size_t kz,
                   int ldK, int Kpass, int tid,
                   u16* Cdst, int Nout, XF&& xf, char* lds)
{
    char* ldsA = lds;
    char* ldsB = lds + 65536;
    const int w = tid >> 6, l = tid & 63;
    const int lr = l & 15, lg = l >> 4;
    const int wr = w >> 2, wc = w & 3;

    int offA[8], offB[4];
    #pragma unroll
    for (int m = 0; m < 8; ++m)
        offA[m] = swz64((wr * 128 + m * 16 + lr) * 64 + lg * 16);
    #pragma unroll
    for (int n = 0; n < 4; ++n)
        offB[n] = swz64((wc * 64 + n * 16 + lr) * 64 + lg * 16);

    const int Ls = swz64(tid * 16);
    const int sr = Ls >> 6, scc = Ls & 63;
    const size_t ldb = (size_t)ldK * 2;
    const char* aS = (const char*)A + (tm + sr) * ldb + kz * 2 + scc;
    const char* bS = (const char*)W + (tn + sr) * ldb + kz * 2 + scc;

    auto AH = [&](int b, int h) -> char* { return ldsA + (b * 2 + h) * 16384; };
    auto BH = [&](int b, int h) -> char* { return ldsB + (b * 2 + h) * 16384; };
    auto stage = [&](char* half, const char* src) {
        gload_lds16(half + w * 1024, src);
        gload_lds16(half + 8192 + w * 1024, src + 128 * ldb);
    };

    const int nt = Kpass >> 6;
    const int niter = nt >> 1;

    f32x4 acc[8][4] = {};
    bf16x8 bq[4];

    stage(AH(0, 0), aS);        stage(BH(0, 0), bS);
    stage(AH(0, 1), aS + 64);   stage(BH(0, 1), bS + 64);
    stage(AH(1, 0), aS + 128);  stage(BH(1, 0), bS + 128);
    asm volatile("s_waitcnt vmcnt(4)" ::: "memory");
    __builtin_amdgcn_s_barrier();

    for (int it = 0; it < niter; ++it) {
        const int t0 = it * 2;
        const bool last = (it == niter - 1);
        #pragma unroll
        for (int p = 0; p < 8; ++p) {
            const int ts = p >> 2;
            const int kk = (p >> 1) & 1, mh = p & 1;

            if (mh == 0) {
                #pragma unroll
                for (int n = 0; n < 4; ++n)
                    bq[n] = *(const bf16x8*)(BH(ts, kk) + offB[n]);
            }
            bf16x8 aF[4];
            #pragma unroll
            for (int q = 0; q < 4; ++q)
                aF[q] = *(const bf16x8*)(AH(ts, kk) + offA[mh * 4 + q]);

            if (p == 0)      { stage(AH(1, 1), aS + (size_t)(t0 + 1) * 128 + 64); }
            else if (p == 1) { stage(BH(1, 1), bS + (size_t)(t0 + 1) * 128 + 64); }
            else if (p == 2) { if (t0 + 2 < nt) stage(AH(0, 0), aS + (size_t)(t0 + 2) * 128); }
            else if (p == 3) { if (t0 + 2 < nt) stage(BH(0, 0), bS + (size_t)(t0 + 2) * 128); }
            else if (p == 4) { if (t0 + 2 < nt) stage(AH(0, 1), aS + (size_t)(t0 + 2) * 128 + 64); }
            else if (p == 5) { if (t0 + 2 < nt) stage(BH(0, 1), bS + (size_t)(t0 + 2) * 128 + 64); }
            else if (p == 6) { if (t0 + 3 < nt) stage(AH(1, 0), aS + (size_t)(t0 + 3) * 128); }
            else             { if (t0 + 3 < nt) stage(BH(1, 0), bS + (size_t)(t0 + 3) * 128); }

            if (p == 3) {
                if (last) asm volatile("s_waitcnt vmcnt(0)" ::: "memory");
                else      asm volatile("s_waitcnt vmcnt(4)" ::: "memory");
            } else if (p == 7 && !last) {
                asm volatile("s_waitcnt vmcnt(4)" ::: "memory");
            }
            __builtin_amdgcn_s_barrier();
            asm volatile("s_waitcnt lgkmcnt(0)");
            __builtin_amdgcn_sched_barrier(0);
            __builtin_amdgcn_s_setprio(1);
            #pragma unroll
            for (int q = 0; q < 4; ++q)
                #pragma unroll
                for (int n = 0; n < 4; ++n)
                    acc[mh * 4 + q][n] = __builtin_amdgcn_mfma_f32_16x16x32_bf16(
                        aF[q], bq[n], acc[mh * 4 + q][n], 0, 0, 0);
            __builtin_amdgcn_s_setprio(0);
        }
    }

    // ---- coalesced epilogue via LDS bounce ----
    __builtin_amdgcn_s_barrier();   // all waves done reading K-loop LDS
    #pragma unroll
    for (int m = 0; m < 8; ++m) {
        #pragma unroll
        for (int n = 0; n < 4; ++n) {
            const int col = wc * 64 + n * 16 + lr;
            #pragma unroll
            for (int j = 0; j < 4; ++j) {
                const int row = wr * 128 + m * 16 + lg * 4 + j;
                const int bo = (row * 512 + col * 2) ^ ((row & 7) << 4);
                *(u16*)(lds + bo) = f2bf(xf(acc[m][n][j], (int)tn + col));
            }
        }
    }
    __syncthreads();
    #pragma unroll
    for (int ps = 0; ps < 16; ++ps) {
        const int L = ps * 8192 + tid * 16;
        const int row = L >> 9;                       // 512B per tile row
        const uint4 v = *(const uint4*)(lds + (L ^ ((row & 7) << 4)));
        *(uint4*)((char*)Cdst + ((tm + row) * (size_t)Nout + tn) * 2 + (L & 511)) = v;
    }
}

// ---------- GEMM 256x256 single (MODE 1=bias, 2=bias+relu, 3=bf16 partial) ----------

template<int MODE, int BSPLIT>
__global__ __launch_bounds__(512) void gemm256_kernel(
    const u16* __restrict__ A, const u16* __restrict__ W,
    const float* __restrict__ bias0, const float* __restrict__ bias1,
    const float* __restrict__ bias2,
    void* __restrict__ Cout,
    void* __restrict__ P1, void* __restrict__ P2, void* __restrict__ P3,
    int N, int ldK, int Kpass)
{
    __shared__ char lds[131072];
    const int tid = threadIdx.x;

    const int nwg = gridDim.x * gridDim.y;
    const int lin = blockIdx.y * gridDim.x + blockIdx.x;
    const int swz = (lin & 7) * (nwg >> 3) + (lin >> 3);
    const size_t tm = (size_t)(swz / gridDim.x) * 256;
    const size_t tn = (size_t)(swz % gridDim.x) * 256;
    const size_t kz = (size_t)blockIdx.z * Kpass;

    u16* Cdst;
    if (MODE == 3) {
        Cdst = (u16*)((blockIdx.z == 0) ? Cout : (blockIdx.z == 1) ? P1 : (blockIdx.z == 2) ? P2 : P3);
    } else {
        Cdst = (u16*)Cout;
    }

    g256_body(A, W, tm, tn, kz, ldK, Kpass, tid, Cdst, N,
        [&](float v, int col) -> float {
            if (MODE == 3) return v;
            float b;
            if (BSPLIT) {
                const float* bp = (col < 1024) ? bias0 : (col < 2048) ? bias1 : bias2;
                b = bp[col & 1023];
            } else {
                b = bias0[col];
            }
            float r = v + b;
            if (MODE == 2) r = fmaxf(r, 0.f);
            return r;
        }, lds);
}

// ---------- FUSED dual GEMM: qkv (192 blocks, N=3072) + crossKV (128, N=2048) ----------

__global__ __launch_bounds__(512) void gemm256_dual_kernel(
    const u16* __restrict__ A0, const u16* __restrict__ W0, u16* __restrict__ C0,
    const float* __restrict__ b0a, const float* __restrict__ b0b, const float* __restrict__ b0c,
    const u16* __restrict__ A1, const u16* __restrict__ W1, u16* __restrict__ C1,
    const float* __restrict__ b1a, const float* __restrict__ b1b)
{
    __shared__ char lds[131072];
    const int tid = threadIdx.x;

    const int nwg = gridDim.x;               // 320
    const int lin = blockIdx.x;
    const int swz = (lin & 7) * (nwg >> 3) + (lin >> 3);

    const bool seg0 = (swz < 192);
    const int t = seg0 ? swz : (swz - 192);
    const int gx = seg0 ? 12 : 8;
    const int Np = seg0 ? 3072 : 2048;
    const u16* A = seg0 ? A0 : A1;
    const u16* W = seg0 ? W0 : W1;
    u16* C = seg0 ? C0 : C1;
    const size_t tm = (size_t)(t / gx) * 256;
    const size_t tn = (size_t)(t % gx) * 256;

    g256_body(A, W, tm, tn, 0, Dm, Dm, tid, C, Np,
        [&](float v, int col) -> float {
            const float* bp = seg0
                ? ((col < 1024) ? b0a : (col < 2048) ? b0b : b0c)
                : ((col < 1024) ? b1a : b1b);
            return v + bp[col & 1023];
        }, lds);
}

// ---------- GEMM 64x128, BK=64, double-buffered 2-phase (N=1024 shapes ONLY) ----------

template<int OUT_BF16, int RELU, int BSPLIT>
__global__ __launch_bounds__(256, 3) void gemm_bt64_kernel(
    const u16* __restrict__ A, const u16* __restrict__ W,
    const float* __restrict__ bias0, const float* __restrict__ bias1,
    const float* __restrict__ bias2,
    void* __restrict__ Cout,
    int N, int K)
{
    __shared__ char Ald[2][8192];
    __shared__ char Bld[2][16384];
    const int tid = threadIdx.x;
    const int w  = tid >> 6, l = tid & 63;
    const int lr = l & 15,  lg = l >> 4;

    const int nwg = gridDim.x * gridDim.y;
    const int lin = blockIdx.y * gridDim.x + blockIdx.x;
    const int swz = (lin & 7) * (nwg >> 3) + (lin >> 3);
    const size_t tm = (size_t)(swz / gridDim.x) * 64;
    const size_t tn = (size_t)(swz % gridDim.x) * 128;

    const int Ls = swz64(tid * 16);
    const int sr = Ls >> 7, sc = (Ls & 127) >> 1;
    const u16* As = A + (tm + sr) * (size_t)K + sc;
    const u16* Bs = W + (tn + sr) * (size_t)K + sc;
    const int woff = w * 1024;

    auto stage = [&](int b, int k0) {
        gload_lds16(Ald[b] + woff,         As + k0);
        gload_lds16(Ald[b] + 4096 + woff,  As + (size_t)32 * K + k0);
        gload_lds16(Bld[b] + woff,         Bs + k0);
        gload_lds16(Bld[b] + 4096 + woff,  Bs + (size_t)32 * K + k0);
        gload_lds16(Bld[b] + 8192 + woff,  Bs + (size_t)64 * K + k0);
        gload_lds16(Bld[b] + 12288 + woff, Bs + (size_t)96 * K + k0);
    };

    int offA[4][2], offB[2][2];
    #pragma unroll
    for (int m = 0; m < 4; ++m)
        #pragma unroll
        for (int kk = 0; kk < 2; ++kk)
            offA[m][kk] = swz64((m * 16 + lr) * 128 + kk * 64 + lg * 16);
    #pragma unroll
    for (int n = 0; n < 2; ++n)
        #pragma unroll
        for (int kk = 0; kk < 2; ++kk)
            offB[n][kk] = swz64((w * 32 + n * 16 + lr) * 128 + kk * 64 + lg * 16);

    f32x4 acc[4][2] = {};
    const int nt = K >> 6;

    stage(0, 0);
    asm volatile("s_waitcnt vmcnt(0)" ::: "memory");
    __syncthreads();

    for (int t = 0; t < nt; ++t) {
        const int cur = t & 1;
        if (t + 1 < nt) stage(cur ^ 1, (t + 1) * 64);
        #pragma unroll
        for (int kk = 0; kk < 2; ++kk) {
            bf16x8 aF[4], bq[2];
            #pragma unroll
            for (int m = 0; m < 4; ++m) aF[m] = *(const bf16x8*)(Ald[cur] + offA[m][kk]);
            #pragma unroll
            for (int n = 0; n < 2; ++n) bq[n] = *(const bf16x8*)(Bld[cur] + offB[n][kk]);
            asm volatile("s_waitcnt lgkmcnt(0)");
            __builtin_amdgcn_sched_barrier(0);
            __builtin_amdgcn_s_setprio(1);
            #pragma unroll
            for (int m = 0; m < 4; ++m)
                #pragma unroll
                for (int n = 0; n < 2; ++n)
                    acc[m][n] = __builtin_amdgcn_mfma_f32_16x16x32_bf16(aF[m], bq[n], acc[m][n], 0, 0, 0);
            __builtin_amdgcn_s_setprio(0);
        }
        if (t + 1 < nt) asm volatile("s_waitcnt vmcnt(0)" ::: "memory");
        __syncthreads();
    }

    float bv[2];
    #pragma unroll
    for (int n = 0; n < 2; ++n) {
        const int col = (int)tn + w * 32 + n * 16 + lr;
        if (BSPLIT) {
            const float* bp = (col < 1024) ? bias0 : (col < 2048) ? bias1 : bias2;
            bv[n] = bp[col & 1023];
        } else {
            bv[n] = bias0[col];
        }
    }

    #pragma unroll
    for (int m = 0; m < 4; ++m) {
        #pragma unroll
        for (int n = 0; n < 2; ++n) {
            const size_t col = tn + w * 32 + n * 16 + lr;
            #pragma unroll
            for (int j = 0; j < 4; ++j) {
                const size_t row = tm + m * 16 + lg * 4 + j;
                float v = acc[m][n][j] + bv[n];
                if (RELU) v = fmaxf(v, 0.f);
                if (OUT_BF16) ((u16*)Cout)[row * (size_t)N + col] = f2bf(v);
                else          ((float*)Cout)[row * (size_t)N + col] = v;
            }
        }
    }
}

// ---------- flash attention (R12/R13 structure, passing — unchanged) ----------

template<int CAUSAL>
__global__ __launch_bounds__(512, 2) void attn_kernel(
    const u16* __restrict__ Qm, int ldq,
    const u16* __restrict__ Km, int ldk,
    const u16* __restrict__ Vm, int ldv,
    u16* __restrict__ Om)
{
    __shared__ char lds[66048];

    const int tid = threadIdx.x;
    const int w = tid >> 6, l = tid & 63;
    const int lq = l & 31, hi = l >> 5;
    const int s = w & 3, hfk = w >> 2;
    const int bh = blockIdx.x;
    const int b = bh >> 4, h = bh & 15;
    const int q0 = (CAUSAL ? (gridDim.y - 1 - blockIdx.y) : blockIdx.y) * 128;
    const int qw0 = q0 + s * 32;
    const size_t baseQ = (size_t)b * Sq * ldq + (size_t)h * 64;
    const size_t baseK = (size_t)b * Sq * ldk + (size_t)h * 64;
    const size_t baseV = (size_t)b * Sq * ldv + (size_t)h * 64;
    const size_t baseO = (size_t)b * Sq * Dm  + (size_t)h * 64;

    const int qrow = qw0 + lq;
    bf16x8 bq[4];
    #pragma unroll
    for (int kc = 0; kc < 4; ++kc)
        bq[kc] = *(const bf16x8*)&Qm[baseQ + (size_t)qrow * ldq + kc * 16 + hi * 8];

    const int tl = tid & 255, pstg = tid >> 8;
    const int kr  = tl >> 2;
    const int kcB = (tl & 3) * 32;
    const int vdg = tl >> 5;
    const int vkp = tl & 31;

    f32x16 o0 = {}, o1 = {};
    float lj = 0.f;

    const int nt_blk  = CAUSAL ? ((q0 + 128) >> 6) : (Sq >> 6);
    const int nrounds = nt_blk >> 1;
    const float cexp = 0.125f * 1.44269504f;
    const float CSH  = 10.0f;

    uint4 ka, kb, va, vb;
    auto loadKV = [&](int rv) {
        const int kv = (rv * 2 + pstg) << 6;
        ka = *(const uint4*)&Km[baseK + (size_t)(kv + kr) * ldk + kcB / 2];
        kb = *(const uint4*)&Km[baseK + (size_t)(kv + kr) * ldk + kcB / 2 + 8];
        va = *(const uint4*)&Vm[baseV + (size_t)(kv + vkp * 2    ) * ldv + vdg * 8];
        vb = *(const uint4*)&Vm[baseV + (size_t)(kv + vkp * 2 + 1) * ldv + vdg * 8];
    };
    auto stageTo = [&](int bsel) {
        char* Kst = lds + bsel * 32768 + pstg * 8192;
        char* Vst = lds + bsel * 32768 + 16384 + pstg * 8192;
        const int sk = (kr & 7) << 4;
        *(uint4*)(Kst + kr * 128 + ((kcB     ) ^ sk)) = ka;
        *(uint4*)(Kst + kr * 128 + ((kcB + 16) ^ sk)) = kb;
        const u16* pa_ = (const u16*)&va;
        const u16* pb_ = (const u16*)&vb;
        #pragma unroll
        for (int i = 0; i < 8; ++i) {
            const int d = vdg * 8 + i;
            unsigned val = (unsigned)pa_[i] | ((unsigned)pb_[i] << 16);
            *(unsigned*)(Vst + d * 128 + ((vkp * 4) ^ ((d & 7) << 4))) = val;
        }
    };

    loadKV(0);
    stageTo(0);
    loadKV(1);
    __syncthreads();

    for (int r = 0; r < nrounds; ++r) {
        const int rp = r & 1;
        const char* Kb_ = lds + rp * 32768 + hfk * 8192;
        const char* Vb_ = lds + rp * 32768 + 16384 + hfk * 8192;
        const int kv0 = (r * 2 + hfk) << 6;
        const bool docmp = (!CAUSAL || kv0 < qw0 + 32);
        const int skq = (lq & 7) << 4;

        f32x16 sv[2];
        if (docmp) {
            sv[0] = (f32x16){}; sv[1] = (f32x16){};
            #pragma unroll
            for (int n = 0; n < 2; ++n) {
                const int rowb = (n * 32 + lq) * 128;
                #pragma unroll
                for (int kc = 0; kc < 4; ++kc) {
                    bf16x8 kf = *(const bf16x8*)(Kb_ + rowb + ((kc * 32 + hi * 16) ^ skq));
                    sv[n] = __builtin_amdgcn_mfma_f32_32x32x16_bf16(kf, bq[kc], sv[n], 0, 0, 0);
                }
            }
        }

        if (r + 1 < nrounds) stageTo(rp ^ 1);
        if (r + 2 < nrounds) loadKV(r + 2);

        if (docmp) {
            const bool diag = CAUSAL && (kv0 + 63 > qw0);
            float rs0 = 0.f, rs1 = 0.f;
            #pragma unroll
            for (int n = 0; n < 2; ++n)
                #pragma unroll
                for (int r2 = 0; r2 < 16; ++r2) {
                    float v = sv[n][r2];
                    if (diag) {
                        int key = kv0 + n * 32 + (r2 & 3) + 8 * (r2 >> 2) + 4 * hi;
                        if (key > qrow) v = -3.0e8f;
                    }
                    float e = fast_exp2(fmaf(v, cexp, -CSH));
                    sv[n][r2] = e;
                    if (r2 & 1) rs1 += e; else rs0 += e;
                }
            float rs = rs0 + rs1;
            rs += __shfl_xor(rs, 32);
            lj += rs;

            unsigned wv[2][8];
            #pragma unroll
            for (int n = 0; n < 2; ++n)
                #pragma unroll
                for (int m = 0; m < 8; ++m)
                    wv[n][m] = cvt_pk_bf16(sv[n][2 * m], sv[n][2 * m + 1]);

            #pragma unroll
            for (int ks = 0; ks < 4; ++ks) {
                const int n = ks >> 1, q_ = (ks & 1) * 4;
                unsigned r0 = (unsigned)__shfl_xor((int)wv[n][q_ + 0], 32);
                unsigned r1 = (unsigned)__shfl_xor((int)wv[n][q_ + 1], 32);
                unsigned r2w = (unsigned)__shfl_xor((int)wv[n][q_ + 2], 32);
                unsigned r3 = (unsigned)__shfl_xor((int)wv[n][q_ + 3], 32);
                union { unsigned u[4]; bf16x8 v; } pa;
                pa.u[0] = hi ? r2w           : wv[n][q_ + 0];
                pa.u[1] = hi ? r3            : wv[n][q_ + 1];
                pa.u[2] = hi ? wv[n][q_ + 2] : r0;
                pa.u[3] = hi ? wv[n][q_ + 3] : r1;
                const int koff = (ks * 32 + hi * 16);
                bf16x8 vf0 = *(const bf16x8*)(Vb_ + lq * 128        + (koff ^ skq));
                bf16x8 vf1 = *(const bf16x8*)(Vb_ + (32 + lq) * 128 + (koff ^ skq));
                o0 = __builtin_amdgcn_mfma_f32_32x32x16_bf16(pa.v, vf0, o0, 0, 0, 0);
                o1 = __builtin_amdgcn_mfma_f32_32x32x16_bf16(pa.v, vf1, o1, 0, 0, 0);
            }
        }
        __syncthreads();
    }

    char* ob = lds + s * 8192 + l * 128;
    float* mlb = (float*)(lds + 65536) + s * 32 + lq;
    const int sko = (l & 7) << 4;

    if (hfk == 1) {
        #pragma unroll
        for (int i = 0; i < 4; ++i) {
            f32x4 t0v = { o0[4 * i], o0[4 * i + 1], o0[4 * i + 2], o0[4 * i + 3] };
            f32x4 t1v = { o1[4 * i], o1[4 * i + 1], o1[4 * i + 2], o1[4 * i + 3] };
            *(f32x4*)(ob + ((i * 16) ^ sko))      = t0v;
            *(f32x4*)(ob + ((64 + i * 16) ^ sko)) = t1v;
        }
        if (hi == 0) mlb[0] = lj;
    }
    __syncthreads();
    if (hfk == 0) {
        const float linv = __builtin_amdgcn_rcpf(lj + mlb[0]);
        f32x4 b0[4], b1[4];
        #pragma unroll
        for (int i = 0; i < 4; ++i) {
            b0[i] = *(const f32x4*)(ob + ((i * 16) ^ sko));
            b1[i] = *(const f32x4*)(ob + ((64 + i * 16) ^ sko));
        }
        #pragma unroll
        for (int r2 = 0; r2 < 16; ++r2) {
            const int crow = (r2 & 3) + 8 * (r2 >> 2) + 4 * hi;
            const float lr_ = __shfl(linv, crow);
            const size_t rowoff = baseO + (size_t)(qw0 + crow) * Dm;
            float v0 = (o0[r2] + b0[r2 >> 2][r2 & 3]) * lr_;
            float v1 = (o1[r2] + b1[r2 >> 2][r2 & 3]) * lr_;
            Om[rowoff + lq]      = f2bf(v0);
            Om[rowoff + 32 + lq] = f2bf(v1);
        }
    }
}

// ---------- add + LayerNorm (bf16 residual stream) ----------

__global__ __launch_bounds__(256) void add_ln_kernel(
    const u16* __restrict__ A, const u16* __restrict__ Bv,
    const float* __restrict__ g, const float* __restrict__ be,
    u16* __restrict__ Y)
{
    const int row = blockIdx.x;
    const int tid = threadIdx.x;
    const size_t off = (size_t)row * Dm;
    ushort4 a4 = ((const ushort4*)(A + off))[tid];
    ushort4 b4 = ((const ushort4*)(Bv + off))[tid];
    float4 xv;
    xv.x = bf2f(a4.x) + bf2f(b4.x);
    xv.y = bf2f(a4.y) + bf2f(b4.y);
    xv.z = bf2f(a4.z) + bf2f(b4.z);
    xv.w = bf2f(a4.w) + bf2f(b4.w);
    float s = xv.x + xv.y + xv.z + xv.w;
    float q = xv.x * xv.x + xv.y * xv.y + xv.z * xv.z + xv.w * xv.w;
    #pragma unroll
    for (int m = 1; m < 64; m <<= 1) {
        s += __shfl_xor(s, m);
        q += __shfl_xor(q, m);
    }
    __shared__ float ss[4], qq[4];
    if ((tid & 63) == 0) { ss[tid >> 6] = s; qq[tid >> 6] = q; }
    __syncthreads();
    s = ss[0] + ss[1] + ss[2] + ss[3];
    q = qq[0] + qq[1] + qq[2] + qq[3];
    const float mean = s * (1.f / 1024.f);
    const float var  = q * (1.f / 1024.f) - mean * mean;
    const float rstd = rsqrtf(var + 1e-5f);
    float4 g4  = ((const float4*)g)[tid];
    float4 be4 = ((const float4*)be)[tid];
    ushort4 ob;
    ob.x = f2bf((xv.x - mean) * rstd * g4.x + be4.x);
    ob.y = f2bf((xv.y - mean) * rstd * g4.y + be4.y);
    ob.z = f2bf((xv.z - mean) * rstd * g4.z + be4.z);
    ob.w = f2bf((xv.w - mean) * rstd * g4.w + be4.w);
    ((ushort4*)(Y + off))[tid] = ob;
}

// ---------- 4-partial (bf16) reduce + bias + add + LayerNorm -> fp32 out ----------

__global__ __launch_bounds__(256) void add_ln_red4_kernel(
    const u16* __restrict__ X,
    const u16* __restrict__ P0, const u16* __restrict__ P1,
    const u16* __restrict__ P2, const u16* __restrict__ P3,
    const float* __restrict__ bias,
    const float* __restrict__ g, const float* __restrict__ be,
    float* __restrict__ Y)
{
    const int row = blockIdx.x;
    const int tid = threadIdx.x;
    const size_t off = (size_t)row * Dm;
    ushort4 a4 = ((const ushort4*)(X + off))[tid];
    ushort4 u0 = ((const ushort4*)(P0 + off))[tid];
    ushort4 u1 = ((const ushort4*)(P1 + off))[tid];
    ushort4 u2 = ((const ushort4*)(P2 + off))[tid];
    ushort4 u3 = ((const ushort4*)(P3 + off))[tid];
    float4 b4 = ((const float4*)bias)[tid];
    float4 xv;
    xv.x = bf2f(a4.x) + bf2f(u0.x) + bf2f(u1.x) + bf2f(u2.x) + bf2f(u3.x) + b4.x;
    xv.y = bf2f(a4.y) + bf2f(u0.y) + bf2f(u1.y) + bf2f(u2.y) + bf2f(u3.y) + b4.y;
    xv.z = bf2f(a4.z) + bf2f(u0.z) + bf2f(u1.z) + bf2f(u2.z) + bf2f(u3.z) + b4.z;
    xv.w = bf2f(a4.w) + bf2f(u0.w) + bf2f(u1.w) + bf2f(u2.w) + bf2f(u3.w) + b4.w;
    float s = xv.x + xv.y + xv.z + xv.w;
    float q = xv.x * xv.x + xv.y * xv.y + xv.z * xv.z + xv.w * xv.w;
    #pragma unroll
    for (int m = 1; m < 64; m <<= 1) {
        s += __shfl_xor(s, m);
        q += __shfl_xor(q, m);
    }
    __shared__ float ss[4], qq[4];
    if ((tid & 63) == 0) { ss[tid >> 6] = s; qq[tid >> 6] = q; }
    __syncthreads();
    s = ss[0] + ss[1] + ss[2] + ss[3];
    q = qq[0] + qq[1] + qq[2] + qq[3];
    const float mean = s * (1.f / 1024.f);
    const float var  = q * (1.f / 1024.f) - mean * mean;
    const float rstd = rsqrtf(var + 1e-5f);
    float4 g4  = ((const float4*)g)[tid];
    float4 be4 = ((const float4*)be)[tid];
    float4 y;
    y.x = (xv.x - mean) * rstd * g4.x + be4.x;
    y.y = (xv.y - mean) * rstd * g4.y + be4.y;
    y.z = (xv.z - mean) * rstd * g4.z + be4.z;
    y.w = (xv.w - mean) * rstd * g4.w + be4.w;
    ((float4*)(Y + off))[tid] = y;
}

// ---------- launch ----------

extern "C" void kernel_launch(void* const* d_in, const int* in_sizes, int n_in,
                              void* d_out, int out_size, void* d_ws, size_t ws_size,
                              hipStream_t stream)
{
    const float* x       = (const float*)d_in[0];
    const float* enc     = (const float*)d_in[1];
    const float* sa_wq   = (const float*)d_in[4];
    const float* sa_bq   = (const float*)d_in[5];
    const float* sa_wk   = (const float*)d_in[6];
    const float* sa_bk   = (const float*)d_in[7];
    const float* sa_wv   = (const float*)d_in[8];
    const float* sa_bv   = (const float*)d_in[9];
    const float* sa_wo   = (const float*)d_in[10];
    const float* sa_bo   = (const float*)d_in[11];
    const float* ca_in_w = (const float*)d_in[12];
    const float* ca_in_b = (const float*)d_in[13];
    const float* ca_out_w= (const float*)d_in[14];
    const float* ca_out_b= (const float*)d_in[15];
    const float* ff_w1   = (const float*)d_in[16];
    const float* ff_b1   = (const float*)d_in[17];
    const float* ff_w2   = (const float*)d_in[18];
    const float* ff_b2   = (const float*)d_in[19];
    const float* n1_g = (const float*)d_in[20];
    const float* n1_b = (const float*)d_in[21];
    const float* n2_g = (const float*)d_in[22];
    const float* n2_b = (const float*)d_in[23];
    const float* n3_g = (const float*)d_in[24];
    const float* n3_b = (const float*)d_in[25];

    char* p = (char*)d_ws;
    auto take = [&](size_t bytes) -> char* {
        char* r = p; p += (bytes + 255) & ~(size_t)255; return r;
    };
    const size_t MDbf = (size_t)Mrows * Dm * 2;
    const size_t DD   = (size_t)Dm * Dm;

    u16* xb     = (u16*)take(MDbf);
    u16* encb   = (u16*)take(MDbf);
    u16* wqkv   = (u16*)take(3 * DD * 2);
    u16* wob    = (u16*)take(DD * 2);
    u16* cainb  = (u16*)take(3 * DD * 2);
    u16* caoutb = (u16*)take(DD * 2);
    u16* fw1b   = (u16*)take((size_t)DFFn * Dm * 2);
    u16* fw2b   = (u16*)take((size_t)Dm * DFFn * 2);
    u16* SCR    = (u16*)take((size_t)Mrows * DFFn * 2);
    u16* AOb    = (u16*)take(MDbf);
    u16* tmpb   = (u16*)take(MDbf);
    u16* x1bf   = (u16*)take(MDbf);
    u16* x2bf   = (u16*)take(MDbf);
    u16* kvbuf  = (u16*)take((size_t)Mrows * 2048 * 2);   // 16MB cross K/V
    if ((size_t)(p - (char*)d_ws) > ws_size) return;

    // ff2 split-K bf16 partials (8 MB each) on buffers dead at ff2 time
    u16* fp0 = AOb;
    u16* fp1 = tmpb;
    u16* fp2 = xb;
    u16* fp3 = encb;

    // ---- one batched cast: 10 segments (sizes in float4 units) ----
    {
        const int sx  = (int)((size_t)Mrows * Dm / 4);
        const int sw  = (int)(DD / 4);
        const int e0 = sx;
        const int e1 = e0 + sx;
        const int e2 = e1 + sw;
        const int e3 = e2 + sw;
        const int e4 = e3 + sw;
        const int e5 = e4 + sw;
        const int e6 = e5 + 3 * sw;
        const int e7 = e6 + sw;
        const int e8 = e7 + 4 * sw;
        const int e9 = e8 + 4 * sw;
        cast_multi_kernel<<<dim3((e9 + 255) / 256), dim3(256), 0, stream>>>(
            x, enc, sa_wq, sa_wk, sa_wv, sa_wo, ca_in_w, ca_out_w, ff_w1, ff_w2,
            xb, encb, wqkv, wqkv + DD, wqkv + 2 * DD, wob, cainb, caoutb, fw1b, fw2b,
            e0, e1, e2, e3, e4, e5, e6, e7, e8, e9);
    }

    const dim3 blk(256);
    const dim3 blk512(512);

    // ---- fused qkv (seg0) + crossKV (seg1): 320 blocks ----
    gemm256_dual_kernel<<<dim3(320), blk512, 0, stream>>>(
        xb, wqkv, SCR, sa_bq, sa_bk, sa_bv,
        encb, cainb + DD, kvbuf, ca_in_b + Dm, ca_in_b + 2 * Dm);

    // ---- self-attention block ----
    attn_kernel<1><<<dim3(4 * Hh, Sq / 128), blk512, 0, stream>>>(SCR, 3072, SCR + 1024, 3072, SCR + 2048, 3072, AOb);
    gemm_bt64_kernel<1, 0, 0><<<dim3(Dm / 128, Mrows / 64), blk, 0, stream>>>(
        AOb, wob, sa_bo, nullptr, nullptr, (void*)tmpb, Dm, Dm);
    add_ln_kernel<<<dim3(Mrows), blk, 0, stream>>>(xb, tmpb, n1_g, n1_b, x1bf);

    // ---- cross-attention block ----
    u16* Qc = SCR;
    gemm_bt64_kernel<1, 0, 0><<<dim3(Dm / 128, Mrows / 64), blk, 0, stream>>>(
        x1bf, cainb, ca_in_b, nullptr, nullptr, (void*)Qc, Dm, Dm);
    attn_kernel<0><<<dim3(4 * Hh, Sq / 128), blk512, 0, stream>>>(Qc, 1024, kvbuf, 2048, kvbuf + 1024, 2048, AOb);
    gemm_bt64_kernel<1, 0, 0><<<dim3(Dm / 128, Mrows / 64), blk, 0, stream>>>(
        AOb, caoutb, ca_out_b, nullptr, nullptr, (void*)tmpb, Dm, Dm);
    add_ln_kernel<<<dim3(Mrows), blk, 0, stream>>>(x1bf, tmpb, n2_g, n2_b, x2bf);

    // ---- feed-forward block ----
    u16* ffh = SCR;
    gemm256_kernel<2, 0><<<dim3(16, 16), blk512, 0, stream>>>(
        x2bf, fw1b, ff_b1, ff_b1, ff_b1, (void*)ffh, nullptr, nullptr, nullptr, DFFn, Dm, Dm);
    gemm256_kernel<3, 0><<<dim3(4, 16, 4), blk512, 0, stream>>>(
        ffh, fw2b, nullptr, nullptr, nullptr, (void*)fp0, (void*)fp1, (void*)fp2, (void*)fp3, Dm, DFFn, 1024);
    add_ln_red4_kernel<<<dim3(Mrows), blk, 0, stream>>>(x2bf, fp0, fp1, fp2, fp3, ff_b2, n3_g, n3_b, (float*)d_out);
}

// Round 21
// 283.550 us; speedup vs baseline: 1.0620x; 1.0620x over previous
//
#include <hip/hip_runtime.h>
#include <hip/hip_bf16.h>
#include <stdint.h>
#include <math.h>

#define DEV static __device__ __forceinline__

typedef short bf16x8 __attribute__((ext_vector_type(8)));
typedef float f32x4 __attribute__((ext_vector_type(4)));
typedef float f32x16 __attribute__((ext_vector_type(16)));
typedef unsigned short u16;

static constexpr int Sq   = 1024;
static constexpr int Dm   = 1024;
static constexpr int Hh   = 16;
static constexpr int Mrows = 4096; // B*S
static constexpr int DFFn = 4096;

// ---------- helpers ----------

DEV u16 f2bf(float f) {  // fp32 -> bf16 (RNE)
    union { float f; unsigned u; } c; c.f = f;
    unsigned u = c.u;
    return (u16)((u + 0x7FFFu + ((u >> 16) & 1u)) >> 16);
}

DEV float bf2f(u16 v) {
    union { unsigned u; float f; } c; c.u = ((unsigned)v) << 16; return c.f;
}

DEV unsigned cvt_pk_bf16(float lo, float hi) {  // D[15:0]=bf16(lo), D[31:16]=bf16(hi)
    unsigned r;
    asm("v_cvt_pk_bf16_f32 %0, %1, %2" : "=v"(r) : "v"(lo), "v"(hi));
    return r;
}

DEV float fast_exp2(float x) {   // raw v_exp_f32, no libm range fixup
#if __has_builtin(__builtin_amdgcn_exp2f)
    return __builtin_amdgcn_exp2f(x);
#else
    float r; asm("v_exp_f32 %0, %1" : "=v"(r) : "v"(x)); return r;
#endif
}

DEV void gload_lds16(void* lds, const void* g) {
    using gvp = __attribute__((address_space(1))) void*;
    using lvp = __attribute__((address_space(3))) void*;
    __builtin_amdgcn_global_load_lds((gvp)const_cast<void*>(g), (lvp)lds, 16, 0, 0);
}

// line-pair swizzle: XOR byte bits 4-6 with (L>>7)&7. Involution, 16B-granular.
DEV int swz64(int L) { return L ^ (((L >> 7) & 7) << 4); }

// ---------- batched fp32 -> bf16 cast (10 segments, one launch) ----------

__global__ __launch_bounds__(256) void cast_multi_kernel(
    const float* s0, const float* s1, const float* s2, const float* s3, const float* s4,
    const float* s5, const float* s6, const float* s7, const float* s8, const float* s9,
    u16* d0, u16* d1, u16* d2, u16* d3, u16* d4,
    u16* d5, u16* d6, u16* d7, u16* d8, u16* d9,
    int e0, int e1, int e2, int e3, int e4,
    int e5, int e6, int e7, int e8, int e9)
{
    int i = blockIdx.x * 256 + threadIdx.x;   // float4 index
    if (i >= e9) return;
    const float* s; u16* d; int b;
    if      (i < e0) { s = s0; d = d0; b = 0;  }
    else if (i < e1) { s = s1; d = d1; b = e0; }
    else if (i < e2) { s = s2; d = d2; b = e1; }
    else if (i < e3) { s = s3; d = d3; b = e2; }
    else if (i < e4) { s = s4; d = d4; b = e3; }
    else if (i < e5) { s = s5; d = d5; b = e4; }
    else if (i < e6) { s = s6; d = d6; b = e5; }
    else if (i < e7) { s = s7; d = d7; b = e6; }
    else if (i < e8) { s = s8; d = d8; b = e7; }
    else             { s = s9; d = d9; b = e8; }
    int j = i - b;
    float4 v = ((const float4*)s)[j];
    ushort4 o;
    o.x = f2bf(v.x); o.y = f2bf(v.y); o.z = f2bf(v.z); o.w = f2bf(v.w);
    ((ushort4*)d)[j] = o;
}

// ---------- shared 8-phase K-loop body (R18 configuration = best measured) ----------

template<typename EPI>
DEV void g256_body(const u16* A, const u16* W, size_t tm, size_t tn, size_t kz,
                   int ldK, int Kpass, int tid, EPI&& epilogue,
                   char* ldsA, char* ldsB)
{
    const int w = tid >> 6, l = tid & 63;
    const int lr = l & 15, lg = l >> 4;
    const int wr = w >> 2, wc = w & 3;

    int offA[8], offB[4];
    #pragma unroll
    for (int m = 0; m < 8; ++m)
        offA[m] = swz64((wr * 128 + m * 16 + lr) * 64 + lg * 16);
    #pragma unroll
    for (int n = 0; n < 4; ++n)
        offB[n] = swz64((wc * 64 + n * 16 + lr) * 64 + lg * 16);

    const int Ls = swz64(tid * 16);
    const int sr = Ls >> 6, scc = Ls & 63;
    const size_t ldb = (size_t)ldK * 2;
    const char* aS = (const char*)A + (tm + sr) * ldb + kz * 2 + scc;
    const char* bS = (const char*)W + (tn + sr) * ldb + kz * 2 + scc;

    auto AH = [&](int b, int h) -> char* { return ldsA + (b * 2 + h) * 16384; };
    auto BH = [&](int b, int h) -> char* { return ldsB + (b * 2 + h) * 16384; };
    auto stage = [&](char* half, const char* src) {
        gload_lds16(half + w * 1024, src);
        gload_lds16(half + 8192 + w * 1024, src + 128 * ldb);
    };

    const int nt = Kpass >> 6;
    const int niter = nt >> 1;

    f32x4 acc[8][4] = {};
    bf16x8 bq[4];

    stage(AH(0, 0), aS);        stage(BH(0, 0), bS);
    stage(AH(0, 1), aS + 64);   stage(BH(0, 1), bS + 64);
    stage(AH(1, 0), aS + 128);  stage(BH(1, 0), bS + 128);
    asm volatile("s_waitcnt vmcnt(4)" ::: "memory");
    __builtin_amdgcn_s_barrier();

    for (int it = 0; it < niter; ++it) {
        const int t0 = it * 2;
        const bool last = (it == niter - 1);
        #pragma unroll
        for (int p = 0; p < 8; ++p) {
            const int ts = p >> 2;
            const int kk = (p >> 1) & 1, mh = p & 1;

            if (mh == 0) {
                #pragma unroll
                for (int n = 0; n < 4; ++n)
                    bq[n] = *(const bf16x8*)(BH(ts, kk) + offB[n]);
            }
            bf16x8 aF[4];
            #pragma unroll
            for (int q = 0; q < 4; ++q)
                aF[q] = *(const bf16x8*)(AH(ts, kk) + offA[mh * 4 + q]);

            if (p == 0)      { stage(AH(1, 1), aS + (size_t)(t0 + 1) * 128 + 64); }
            else if (p == 1) { stage(BH(1, 1), bS + (size_t)(t0 + 1) * 128 + 64); }
            else if (p == 2) { if (t0 + 2 < nt) stage(AH(0, 0), aS + (size_t)(t0 + 2) * 128); }
            else if (p == 3) { if (t0 + 2 < nt) stage(BH(0, 0), bS + (size_t)(t0 + 2) * 128); }
            else if (p == 4) { if (t0 + 2 < nt) stage(AH(0, 1), aS + (size_t)(t0 + 2) * 128 + 64); }
            else if (p == 5) { if (t0 + 2 < nt) stage(BH(0, 1), bS + (size_t)(t0 + 2) * 128 + 64); }
            else if (p == 6) { if (t0 + 3 < nt) stage(AH(1, 0), aS + (size_t)(t0 + 3) * 128); }
            else             { if (t0 + 3 < nt) stage(BH(1, 0), bS + (size_t)(t0 + 3) * 128); }

            if (p == 3) {
                if (last) asm volatile("s_waitcnt vmcnt(0)" ::: "memory");
                else      asm volatile("s_waitcnt vmcnt(4)" ::: "memory");
            } else if (p == 7 && !last) {
                asm volatile("s_waitcnt vmcnt(4)" ::: "memory");
            }
            __builtin_amdgcn_s_barrier();
            asm volatile("s_waitcnt lgkmcnt(0)");
            __builtin_amdgcn_sched_barrier(0);
            __builtin_amdgcn_s_setprio(1);
            #pragma unroll
            for (int q = 0; q < 4; ++q)
                #pragma unroll
                for (int n = 0; n < 4; ++n)
                    acc[mh * 4 + q][n] = __builtin_amdgcn_mfma_f32_16x16x32_bf16(
                        aF[q], bq[n], acc[mh * 4 + q][n], 0, 0, 0);
            __builtin_amdgcn_s_setprio(0);
        }
    }

    epilogue(acc, wr, wc, lr, lg);
}

// ---------- GEMM 256x256 single (MODE 1=bias, 2=bias+relu, 3=bf16 partial) ----------

template<int MODE, int BSPLIT>
__global__ __launch_bounds__(512) void gemm256_kernel(
    const u16* __restrict__ A, const u16* __restrict__ W,
    const float* __restrict__ bias0, const float* __restrict__ bias1,
    const float* __restrict__ bias2,
    void* __restrict__ Cout,
    void* __restrict__ P1, void* __restrict__ P2, void* __restrict__ P3,
    int N, int ldK, int Kpass)
{
    __shared__ char ldsA[65536];
    __shared__ char ldsB[65536];
    const int tid = threadIdx.x;

    const int nwg = gridDim.x * gridDim.y;
    const int lin = blockIdx.y * gridDim.x + blockIdx.x;
    const int swz = (lin & 7) * (nwg >> 3) + (lin >> 3);
    const size_t tm = (size_t)(swz / gridDim.x) * 256;
    const size_t tn = (size_t)(swz % gridDim.x) * 256;
    const size_t kz = (size_t)blockIdx.z * Kpass;

    g256_body(A, W, tm, tn, kz, ldK, Kpass, tid,
        [&](f32x4 (&acc)[8][4], int wr, int wc, int lr, int lg) {
            u16* Pp = nullptr;
            float bv[4];
            if (MODE == 3) {
                Pp = (u16*)((blockIdx.z == 0) ? Cout : (blockIdx.z == 1) ? P1 : (blockIdx.z == 2) ? P2 : P3);
            } else {
                #pragma unroll
                for (int n = 0; n < 4; ++n) {
                    const int col = (int)tn + wc * 64 + n * 16 + lr;
                    if (BSPLIT) {
                        const float* bp = (col < 1024) ? bias0 : (col < 2048) ? bias1 : bias2;
                        bv[n] = bp[col & 1023];
                    } else {
                        bv[n] = bias0[col];
                    }
                }
            }
            #pragma unroll
            for (int m = 0; m < 8; ++m) {
                #pragma unroll
                for (int n = 0; n < 4; ++n) {
                    const size_t col = tn + wc * 64 + n * 16 + lr;
                    #pragma unroll
                    for (int j = 0; j < 4; ++j) {
                        const size_t row = tm + wr * 128 + m * 16 + lg * 4 + j;
                        if (MODE == 3) {
                            Pp[row * (size_t)N + col] = f2bf(acc[m][n][j]);
                        } else {
                            float v = acc[m][n][j] + bv[n];
                            if (MODE == 2) v = fmaxf(v, 0.f);
                            ((u16*)Cout)[row * (size_t)N + col] = f2bf(v);
                        }
                    }
                }
            }
        }, ldsA, ldsB);
}

// ---------- FUSED dual GEMM: qkv (192 blocks, N=3072) + crossKV (128, N=2048) ----------

__global__ __launch_bounds__(512) void gemm256_dual_kernel(
    const u16* __restrict__ A0, const u16* __restrict__ W0, u16* __restrict__ C0,
    const float* __restrict__ b0a, const float* __restrict__ b0b, const float* __restrict__ b0c,
    const u16* __restrict__ A1, const u16* __restrict__ W1, u16* __restrict__ C1,
    const float* __restrict__ b1a, const float* __restrict__ b1b)
{
    __shared__ char ldsA[65536];
    __shared__ char ldsB[65536];
    const int tid = threadIdx.x;

    const int nwg = gridDim.x;               // 320
    const int lin = blockIdx.x;
    const int swz = (lin & 7) * (nwg >> 3) + (lin >> 3);

    const bool seg0 = (swz < 192);
    const int t = seg0 ? swz : (swz - 192);
    const int gx = seg0 ? 12 : 8;
    const int Np = seg0 ? 3072 : 2048;
    const u16* A = seg0 ? A0 : A1;
    const u16* W = seg0 ? W0 : W1;
    u16* C = seg0 ? C0 : C1;
    const size_t tm = (size_t)(t / gx) * 256;
    const size_t tn = (size_t)(t % gx) * 256;

    g256_body(A, W, tm, tn, 0, Dm, Dm, tid,
        [&](f32x4 (&acc)[8][4], int wr, int wc, int lr, int lg) {
            float bv[4];
            #pragma unroll
            for (int n = 0; n < 4; ++n) {
                const int col = (int)tn + wc * 64 + n * 16 + lr;
                const float* bp = seg0
                    ? ((col < 1024) ? b0a : (col < 2048) ? b0b : b0c)
                    : ((col < 1024) ? b1a : b1b);
                bv[n] = bp[col & 1023];
            }
            #pragma unroll
            for (int m = 0; m < 8; ++m) {
                #pragma unroll
                for (int n = 0; n < 4; ++n) {
                    const size_t col = tn + wc * 64 + n * 16 + lr;
                    #pragma unroll
                    for (int j = 0; j < 4; ++j) {
                        const size_t row = tm + wr * 128 + m * 16 + lg * 4 + j;
                        C[row * (size_t)Np + col] = f2bf(acc[m][n][j] + bv[n]);
                    }
                }
            }
        }, ldsA, ldsB);
}

// ---------- GEMM 64x128, BK=64, double-buffered 2-phase (N=1024 shapes ONLY) ----------

template<int OUT_BF16, int RELU, int BSPLIT>
__global__ __launch_bounds__(256, 3) void gemm_bt64_kernel(
    const u16* __restrict__ A, const u16* __restrict__ W,
    const float* __restrict__ bias0, const float* __restrict__ bias1,
    const float* __restrict__ bias2,
    void* __restrict__ Cout,
    int N, int K)
{
    __shared__ char Ald[2][8192];
    __shared__ char Bld[2][16384];
    const int tid = threadIdx.x;
    const int w  = tid >> 6, l = tid & 63;
    const int lr = l & 15,  lg = l >> 4;

    const int nwg = gridDim.x * gridDim.y;
    const int lin = blockIdx.y * gridDim.x + blockIdx.x;
    const int swz = (lin & 7) * (nwg >> 3) + (lin >> 3);
    const size_t tm = (size_t)(swz / gridDim.x) * 64;
    const size_t tn = (size_t)(swz % gridDim.x) * 128;

    const int Ls = swz64(tid * 16);
    const int sr = Ls >> 7, sc = (Ls & 127) >> 1;
    const u16* As = A + (tm + sr) * (size_t)K + sc;
    const u16* Bs = W + (tn + sr) * (size_t)K + sc;
    const int woff = w * 1024;

    auto stage = [&](int b, int k0) {
        gload_lds16(Ald[b] + woff,         As + k0);
        gload_lds16(Ald[b] + 4096 + woff,  As + (size_t)32 * K + k0);
        gload_lds16(Bld[b] + woff,         Bs + k0);
        gload_lds16(Bld[b] + 4096 + woff,  Bs + (size_t)32 * K + k0);
        gload_lds16(Bld[b] + 8192 + woff,  Bs + (size_t)64 * K + k0);
        gload_lds16(Bld[b] + 12288 + woff, Bs + (size_t)96 * K + k0);
    };

    int offA[4][2], offB[2][2];
    #pragma unroll
    for (int m = 0; m < 4; ++m)
        #pragma unroll
        for (int kk = 0; kk < 2; ++kk)
            offA[m][kk] = swz64((m * 16 + lr) * 128 + kk * 64 + lg * 16);
    #pragma unroll
    for (int n = 0; n < 2; ++n)
        #pragma unroll
        for (int kk = 0; kk < 2; ++kk)
            offB[n][kk] = swz64((w * 32 + n * 16 + lr) * 128 + kk * 64 + lg * 16);

    f32x4 acc[4][2] = {};
    const int nt = K >> 6;

    stage(0, 0);
    asm volatile("s_waitcnt vmcnt(0)" ::: "memory");
    __syncthreads();

    for (int t = 0; t < nt; ++t) {
        const int cur = t & 1;
        if (t + 1 < nt) stage(cur ^ 1, (t + 1) * 64);
        #pragma unroll
        for (int kk = 0; kk < 2; ++kk) {
            bf16x8 aF[4], bq[2];
            #pragma unroll
            for (int m = 0; m < 4; ++m) aF[m] = *(const bf16x8*)(Ald[cur] + offA[m][kk]);
            #pragma unroll
            for (int n = 0; n < 2; ++n) bq[n] = *(const bf16x8*)(Bld[cur] + offB[n][kk]);
            asm volatile("s_waitcnt lgkmcnt(0)");
            __builtin_amdgcn_sched_barrier(0);
            __builtin_amdgcn_s_setprio(1);
            #pragma unroll
            for (int m = 0; m < 4; ++m)
                #pragma unroll
                for (int n = 0; n < 2; ++n)
                    acc[m][n] = __builtin_amdgcn_mfma_f32_16x16x32_bf16(aF[m], bq[n], acc[m][n], 0, 0, 0);
            __builtin_amdgcn_s_setprio(0);
        }
        if (t + 1 < nt) asm volatile("s_waitcnt vmcnt(0)" ::: "memory");
        __syncthreads();
    }

    float bv[2];
    #pragma unroll
    for (int n = 0; n < 2; ++n) {
        const int col = (int)tn + w * 32 + n * 16 + lr;
        if (BSPLIT) {
            const float* bp = (col < 1024) ? bias0 : (col < 2048) ? bias1 : bias2;
            bv[n] = bp[col & 1023];
        } else {
            bv[n] = bias0[col];
        }
    }

    #pragma unroll
    for (int m = 0; m < 4; ++m) {
        #pragma unroll
        for (int n = 0; n < 2; ++n) {
            const size_t col = tn + w * 32 + n * 16 + lr;
            #pragma unroll
            for (int j = 0; j < 4; ++j) {
                const size_t row = tm + m * 16 + lg * 4 + j;
                float v = acc[m][n][j] + bv[n];
                if (RELU) v = fmaxf(v, 0.f);
                if (OUT_BF16) ((u16*)Cout)[row * (size_t)N + col] = f2bf(v);
                else          ((float*)Cout)[row * (size_t)N + col] = v;
            }
        }
    }
}

// ---------- flash attention (R12/R13 structure, passing — unchanged) ----------

template<int CAUSAL>
__global__ __launch_bounds__(512, 2) void attn_kernel(
    const u16* __restrict__ Qm, int ldq,
    const u16* __restrict__ Km, int ldk,
    const u16* __restrict__ Vm, int ldv,
    u16* __restrict__ Om)
{
    __shared__ char lds[66048];

    const int tid = threadIdx.x;
    const int w = tid >> 6, l = tid & 63;
    const int lq = l & 31, hi = l >> 5;
    const int s = w & 3, hfk = w >> 2;
    const int bh = blockIdx.x;
    const int b = bh >> 4, h = bh & 15;
    const int q0 = (CAUSAL ? (gridDim.y - 1 - blockIdx.y) : blockIdx.y) * 128;
    const int qw0 = q0 + s * 32;
    const size_t baseQ = (size_t)b * Sq * ldq + (size_t)h * 64;
    const size_t baseK = (size_t)b * Sq * ldk + (size_t)h * 64;
    const size_t baseV = (size_t)b * Sq * ldv + (size_t)h * 64;
    const size_t baseO = (size_t)b * Sq * Dm  + (size_t)h * 64;

    const int qrow = qw0 + lq;
    bf16x8 bq[4];
    #pragma unroll
    for (int kc = 0; kc < 4; ++kc)
        bq[kc] = *(const bf16x8*)&Qm[baseQ + (size_t)qrow * ldq + kc * 16 + hi * 8];

    const int tl = tid & 255, pstg = tid >> 8;
    const int kr  = tl >> 2;
    const int kcB = (tl & 3) * 32;
    const int vdg = tl >> 5;
    const int vkp = tl & 31;

    f32x16 o0 = {}, o1 = {};
    float lj = 0.f;

    const int nt_blk  = CAUSAL ? ((q0 + 128) >> 6) : (Sq >> 6);
    const int nrounds = nt_blk >> 1;
    const float cexp = 0.125f * 1.44269504f;
    const float CSH  = 10.0f;

    uint4 ka, kb, va, vb;
    auto loadKV = [&](int rv) {
        const int kv = (rv * 2 + pstg) << 6;
        ka = *(const uint4*)&Km[baseK + (size_t)(kv + kr) * ldk + kcB / 2];
        kb = *(const uint4*)&Km[baseK + (size_t)(kv + kr) * ldk + kcB / 2 + 8];
        va = *(const uint4*)&Vm[baseV + (size_t)(kv + vkp * 2    ) * ldv + vdg * 8];
        vb = *(const uint4*)&Vm[baseV + (size_t)(kv + vkp * 2 + 1) * ldv + vdg * 8];
    };
    auto stageTo = [&](int bsel) {
        char* Kst = lds + bsel * 32768 + pstg * 8192;
        char* Vst = lds + bsel * 32768 + 16384 + pstg * 8192;
        const int sk = (kr & 7) << 4;
        *(uint4*)(Kst + kr * 128 + ((kcB     ) ^ sk)) = ka;
        *(uint4*)(Kst + kr * 128 + ((kcB + 16) ^ sk)) = kb;
        const u16* pa_ = (const u16*)&va;
        const u16* pb_ = (const u16*)&vb;
        #pragma unroll
        for (int i = 0; i < 8; ++i) {
            const int d = vdg * 8 + i;
            unsigned val = (unsigned)pa_[i] | ((unsigned)pb_[i] << 16);
            *(unsigned*)(Vst + d * 128 + ((vkp * 4) ^ ((d & 7) << 4))) = val;
        }
    };

    loadKV(0);
    stageTo(0);
    loadKV(1);
    __syncthreads();

    for (int r = 0; r < nrounds; ++r) {
        const int rp = r & 1;
        const char* Kb_ = lds + rp * 32768 + hfk * 8192;
        const char* Vb_ = lds + rp * 32768 + 16384 + hfk * 8192;
        const int kv0 = (r * 2 + hfk) << 6;
        const bool docmp = (!CAUSAL || kv0 < qw0 + 32);
        const int skq = (lq & 7) << 4;

        f32x16 sv[2];
        if (docmp) {
            sv[0] = (f32x16){}; sv[1] = (f32x16){};
            #pragma unroll
            for (int n = 0; n < 2; ++n) {
                const int rowb = (n * 32 + lq) * 128;
                #pragma unroll
                for (int kc = 0; kc < 4; ++kc) {
                    bf16x8 kf = *(const bf16x8*)(Kb_ + rowb + ((kc * 32 + hi * 16) ^ skq));
                    sv[n] = __builtin_amdgcn_mfma_f32_32x32x16_bf16(kf, bq[kc], sv[n], 0, 0, 0);
                }
            }
        }

        if (r + 1 < nrounds) stageTo(rp ^ 1);
        if (r + 2 < nrounds) loadKV(r + 2);

        if (docmp) {
            const bool diag = CAUSAL && (kv0 + 63 > qw0);
            float rs0 = 0.f, rs1 = 0.f;
            #pragma unroll
            for (int n = 0; n < 2; ++n)
                #pragma unroll
                for (int r2 = 0; r2 < 16; ++r2) {
                    float v = sv[n][r2];
                    if (diag) {
                        int key = kv0 + n * 32 + (r2 & 3) + 8 * (r2 >> 2) + 4 * hi;
                        if (key > qrow) v = -3.0e8f;
                    }
                    float e = fast_exp2(fmaf(v, cexp, -CSH));
                    sv[n][r2] = e;
                    if (r2 & 1) rs1 += e; else rs0 += e;
                }
            float rs = rs0 + rs1;
            rs += __shfl_xor(rs, 32);
            lj += rs;

            unsigned wv[2][8];
            #pragma unroll
            for (int n = 0; n < 2; ++n)
                #pragma unroll
                for (int m = 0; m < 8; ++m)
                    wv[n][m] = cvt_pk_bf16(sv[n][2 * m], sv[n][2 * m + 1]);

            #pragma unroll
            for (int ks = 0; ks < 4; ++ks) {
                const int n = ks >> 1, q_ = (ks & 1) * 4;
                unsigned r0 = (unsigned)__shfl_xor((int)wv[n][q_ + 0], 32);
                unsigned r1 = (unsigned)__shfl_xor((int)wv[n][q_ + 1], 32);
                unsigned r2w = (unsigned)__shfl_xor((int)wv[n][q_ + 2], 32);
                unsigned r3 = (unsigned)__shfl_xor((int)wv[n][q_ + 3], 32);
                union { unsigned u[4]; bf16x8 v; } pa;
                pa.u[0] = hi ? r2w           : wv[n][q_ + 0];
                pa.u[1] = hi ? r3            : wv[n][q_ + 1];
                pa.u[2] = hi ? wv[n][q_ + 2] : r0;
                pa.u[3] = hi ? wv[n][q_ + 3] : r1;
                const int koff = (ks * 32 + hi * 16);
                bf16x8 vf0 = *(const bf16x8*)(Vb_ + lq * 128        + (koff ^ skq));
                bf16x8 vf1 = *(const bf16x8*)(Vb_ + (32 + lq) * 128 + (koff ^ skq));
                o0 = __builtin_amdgcn_mfma_f32_32x32x16_bf16(pa.v, vf0, o0, 0, 0, 0);
                o1 = __builtin_amdgcn_mfma_f32_32x32x16_bf16(pa.v, vf1, o1, 0, 0, 0);
            }
        }
        __syncthreads();
    }

    char* ob = lds + s * 8192 + l * 128;
    float* mlb = (float*)(lds + 65536) + s * 32 + lq;
    const int sko = (l & 7) << 4;

    if (hfk == 1) {
        #pragma unroll
        for (int i = 0; i < 4; ++i) {
            f32x4 t0v = { o0[4 * i], o0[4 * i + 1], o0[4 * i + 2], o0[4 * i + 3] };
            f32x4 t1v = { o1[4 * i], o1[4 * i + 1], o1[4 * i + 2], o1[4 * i + 3] };
            *(f32x4*)(ob + ((i * 16) ^ sko))      = t0v;
            *(f32x4*)(ob + ((64 + i * 16) ^ sko)) = t1v;
        }
        if (hi == 0) mlb[0] = lj;
    }
    __syncthreads();
    if (hfk == 0) {
        const float linv = __builtin_amdgcn_rcpf(lj + mlb[0]);
        f32x4 b0[4], b1[4];
        #pragma unroll
        for (int i = 0; i < 4; ++i) {
            b0[i] = *(const f32x4*)(ob + ((i * 16) ^ sko));
            b1[i] = *(const f32x4*)(ob + ((64 + i * 16) ^ sko));
        }
        #pragma unroll
        for (int r2 = 0; r2 < 16; ++r2) {
            const int crow = (r2 & 3) + 8 * (r2 >> 2) + 4 * hi;
            const float lr_ = __shfl(linv, crow);
            const size_t rowoff = baseO + (size_t)(qw0 + crow) * Dm;
            float v0 = (o0[r2] + b0[r2 >> 2][r2 & 3]) * lr_;
            float v1 = (o1[r2] + b1[r2 >> 2][r2 & 3]) * lr_;
            Om[rowoff + lq]      = f2bf(v0);
            Om[rowoff + 32 + lq] = f2bf(v1);
        }
    }
}

// ---------- add + LayerNorm (bf16 residual stream) ----------

__global__ __launch_bounds__(256) void add_ln_kernel(
    const u16* __restrict__ A, const u16* __restrict__ Bv,
    const float* __restrict__ g, const float* __restrict__ be,
    u16* __restrict__ Y)
{
    const int row = blockIdx.x;
    const int tid = threadIdx.x;
    const size_t off = (size_t)row * Dm;
    ushort4 a4 = ((const ushort4*)(A + off))[tid];
    ushort4 b4 = ((const ushort4*)(Bv + off))[tid];
    float4 xv;
    xv.x = bf2f(a4.x) + bf2f(b4.x);
    xv.y = bf2f(a4.y) + bf2f(b4.y);
    xv.z = bf2f(a4.z) + bf2f(b4.z);
    xv.w = bf2f(a4.w) + bf2f(b4.w);
    float s = xv.x + xv.y + xv.z + xv.w;
    float q = xv.x * xv.x + xv.y * xv.y + xv.z * xv.z + xv.w * xv.w;
    #pragma unroll
    for (int m = 1; m < 64; m <<= 1) {
        s += __shfl_xor(s, m);
        q += __shfl_xor(q, m);
    }
    __shared__ float ss[4], qq[4];
    if ((tid & 63) == 0) { ss[tid >> 6] = s; qq[tid >> 6] = q; }
    __syncthreads();
    s = ss[0] + ss[1] + ss[2] + ss[3];
    q = qq[0] + qq[1] + qq[2] + qq[3];
    const float mean = s * (1.f / 1024.f);
    const float var  = q * (1.f / 1024.f) - mean * mean;
    const float rstd = rsqrtf(var + 1e-5f);
    float4 g4  = ((const float4*)g)[tid];
    float4 be4 = ((const float4*)be)[tid];
    ushort4 ob;
    ob.x = f2bf((xv.x - mean) * rstd * g4.x + be4.x);
    ob.y = f2bf((xv.y - mean) * rstd * g4.y + be4.y);
    ob.z = f2bf((xv.z - mean) * rstd * g4.z + be4.z);
    ob.w = f2bf((xv.w - mean) * rstd * g4.w + be4.w);
    ((ushort4*)(Y + off))[tid] = ob;
}

// ---------- 4-partial (bf16) reduce + bias + add + LayerNorm -> fp32 out ----------

__global__ __launch_bounds__(256) void add_ln_red4_kernel(
    const u16* __restrict__ X,
    const u16* __restrict__ P0, const u16* __restrict__ P1,
    const u16* __restrict__ P2, const u16* __restrict__ P3,
    const float* __restrict__ bias,
    const float* __restrict__ g, const float* __restrict__ be,
    float* __restrict__ Y)
{
    const int row = blockIdx.x;
    const int tid = threadIdx.x;
    const size_t off = (size_t)row * Dm;
    ushort4 a4 = ((const ushort4*)(X + off))[tid];
    ushort4 u0 = ((const ushort4*)(P0 + off))[tid];
    ushort4 u1 = ((const ushort4*)(P1 + off))[tid];
    ushort4 u2 = ((const ushort4*)(P2 + off))[tid];
    ushort4 u3 = ((const ushort4*)(P3 + off))[tid];
    float4 b4 = ((const float4*)bias)[tid];
    float4 xv;
    xv.x = bf2f(a4.x) + bf2f(u0.x) + bf2f(u1.x) + bf2f(u2.x) + bf2f(u3.x) + b4.x;
    xv.y = bf2f(a4.y) + bf2f(u0.y) + bf2f(u1.y) + bf2f(u2.y) + bf2f(u3.y) + b4.y;
    xv.z = bf2f(a4.z) + bf2f(u0.z) + bf2f(u1.z) + bf2f(u2.z) + bf2f(u3.z) + b4.z;
    xv.w = bf2f(a4.w) + bf2f(u0.w) + bf2f(u1.w) + bf2f(u2.w) + bf2f(u3.w) + b4.w;
    float s = xv.x + xv.y + xv.z + xv.w;
    float q = xv.x * xv.x + xv.y * xv.y + xv.z * xv.z + xv.w * xv.w;
    #pragma unroll
    for (int m = 1; m < 64; m <<= 1) {
        s += __shfl_xor(s, m);
        q += __shfl_xor(q, m);
    }
    __shared__ float ss[4], qq[4];
    if ((tid & 63) == 0) { ss[tid >> 6] = s; qq[tid >> 6] = q; }
    __syncthreads();
    s = ss[0] + ss[1] + ss[2] + ss[3];
    q = qq[0] + qq[1] + qq[2] + qq[3];
    const float mean = s * (1.f / 1024.f);
    const float var  = q * (1.f / 1024.f) - mean * mean;
    const float rstd = rsqrtf(var + 1e-5f);
    float4 g4  = ((const float4*)g)[tid];
    float4 be4 = ((const float4*)be)[tid];
    float4 y;
    y.x = (xv.x - mean) * rstd * g4.x + be4.x;
    y.y = (xv.y - mean) * rstd * g4.y + be4.y;
    y.z = (xv.z - mean) * rstd * g4.z + be4.z;
    y.w = (xv.w - mean) * rstd * g4.w + be4.w;
    ((float4*)(Y + off))[tid] = y;
}

// ---------- launch ----------

extern "C" void kernel_launch(void* const* d_in, const int* in_sizes, int n_in,
                              void* d_out, int out_size, void* d_ws, size_t ws_size,
                              hipStream_t stream)
{
    const float* x       = (const float*)d_in[0];
    const float* enc     = (const float*)d_in[1];
    const float* sa_wq   = (const float*)d_in[4];
    const float* sa_bq   = (const float*)d_in[5];
    const float* sa_wk   = (const float*)d_in[6];
    const float* sa_bk   = (const float*)d_in[7];
    const float* sa_wv   = (const float*)d_in[8];
    const float* sa_bv   = (const float*)d_in[9];
    const float* sa_wo   = (const float*)d_in[10];
    const float* sa_bo   = (const float*)d_in[11];
    const float* ca_in_w = (const float*)d_in[12];
    const float* ca_in_b = (const float*)d_in[13];
    const float* ca_out_w= (const float*)d_in[14];
    const float* ca_out_b= (const float*)d_in[15];
    const float* ff_w1   = (const float*)d_in[16];
    const float* ff_b1   = (const float*)d_in[17];
    const float* ff_w2   = (const float*)d_in[18];
    const float* ff_b2   = (const float*)d_in[19];
    const float* n1_g = (const float*)d_in[20];
    const float* n1_b = (const float*)d_in[21];
    const float* n2_g = (const float*)d_in[22];
    const float* n2_b = (const float*)d_in[23];
    const float* n3_g = (const float*)d_in[24];
    const float* n3_b = (const float*)d_in[25];

    char* p = (char*)d_ws;
    auto take = [&](size_t bytes) -> char* {
        char* r = p; p += (bytes + 255) & ~(size_t)255; return r;
    };
    const size_t MDbf = (size_t)Mrows * Dm * 2;
    const size_t DD   = (size_t)Dm * Dm;

    u16* xb     = (u16*)take(MDbf);
    u16* encb   = (u16*)take(MDbf);
    u16* wqkv   = (u16*)take(3 * DD * 2);
    u16* wob    = (u16*)take(DD * 2);
    u16* cainb  = (u16*)take(3 * DD * 2);
    u16* caoutb = (u16*)take(DD * 2);
    u16* fw1b   = (u16*)take((size_t)DFFn * Dm * 2);
    u16* fw2b   = (u16*)take((size_t)Dm * DFFn * 2);
    u16* SCR    = (u16*)take((size_t)Mrows * DFFn * 2);
    u16* AOb    = (u16*)take(MDbf);
    u16* tmpb   = (u16*)take(MDbf);
    u16* x1bf   = (u16*)take(MDbf);
    u16* x2bf   = (u16*)take(MDbf);
    u16* kvbuf  = (u16*)take((size_t)Mrows * 2048 * 2);   // 16MB cross K/V
    if ((size_t)(p - (char*)d_ws) > ws_size) return;

    // ff2 split-K bf16 partials (8 MB each) on buffers dead at ff2 time
    u16* fp0 = AOb;
    u16* fp1 = tmpb;
    u16* fp2 = xb;
    u16* fp3 = encb;

    // ---- one batched cast: 10 segments (sizes in float4 units) ----
    {
        const int sx  = (int)((size_t)Mrows * Dm / 4);
        const int sw  = (int)(DD / 4);
        const int e0 = sx;
        const int e1 = e0 + sx;
        const int e2 = e1 + sw;
        const int e3 = e2 + sw;
        const int e4 = e3 + sw;
        const int e5 = e4 + sw;
        const int e6 = e5 + 3 * sw;
        const int e7 = e6 + sw;
        const int e8 = e7 + 4 * sw;
        const int e9 = e8 + 4 * sw;
        cast_multi_kernel<<<dim3((e9 + 255) / 256), dim3(256), 0, stream>>>(
            x, enc, sa_wq, sa_wk, sa_wv, sa_wo, ca_in_w, ca_out_w, ff_w1, ff_w2,
            xb, encb, wqkv, wqkv + DD, wqkv + 2 * DD, wob, cainb, caoutb, fw1b, fw2b,
            e0, e1, e2, e3, e4, e5, e6, e7, e8, e9);
    }

    const dim3 blk(256);
    const dim3 blk512(512);

    // ---- fused qkv (seg0) + crossKV (seg1): 320 blocks ----
    gemm256_dual_kernel<<<dim3(320), blk512, 0, stream>>>(
        xb, wqkv, SCR, sa_bq, sa_bk, sa_bv,
        encb, cainb + DD, kvbuf, ca_in_b + Dm, ca_in_b + 2 * Dm);

    // ---- self-attention block ----
    attn_kernel<1><<<dim3(4 * Hh, Sq / 128), blk512, 0, stream>>>(SCR, 3072, SCR + 1024, 3072, SCR + 2048, 3072, AOb);
    gemm_bt64_kernel<1, 0, 0><<<dim3(Dm / 128, Mrows / 64), blk, 0, stream>>>(
        AOb, wob, sa_bo, nullptr, nullptr, (void*)tmpb, Dm, Dm);
    add_ln_kernel<<<dim3(Mrows), blk, 0, stream>>>(xb, tmpb, n1_g, n1_b, x1bf);

    // ---- cross-attention block ----
    u16* Qc = SCR;
    gemm_bt64_kernel<1, 0, 0><<<dim3(Dm / 128, Mrows / 64), blk, 0, stream>>>(
        x1bf, cainb, ca_in_b, nullptr, nullptr, (void*)Qc, Dm, Dm);
    attn_kernel<0><<<dim3(4 * Hh, Sq / 128), blk512, 0, stream>>>(Qc, 1024, kvbuf, 2048, kvbuf + 1024, 2048, AOb);
    gemm_bt64_kernel<1, 0, 0><<<dim3(Dm / 128, Mrows / 64), blk, 0, stream>>>(
        AOb, caoutb, ca_out_b, nullptr, nullptr, (void*)tmpb, Dm, Dm);
    add_ln_kernel<<<dim3(Mrows), blk, 0, stream>>>(x1bf, tmpb, n2_g, n2_b, x2bf);

    // ---- feed-forward block ----
    u16* ffh = SCR;
    gemm256_kernel<2, 0><<<dim3(16, 16), blk512, 0, stream>>>(
        x2bf, fw1b, ff_b1, ff_b1, ff_b1, (void*)ffh, nullptr, nullptr, nullptr, DFFn, Dm, Dm);
    gemm256_kernel<3, 0><<<dim3(4, 16, 4), blk512, 0, stream>>>(
        ffh, fw2b, nullptr, nullptr, nullptr, (void*)fp0, (void*)fp1, (void*)fp2, (void*)fp3, Dm, DFFn, 1024);
    add_ln_red4_kernel<<<dim3(Mrows), blk, 0, stream>>>(x2bf, fp0, fp1, fp2, fp3, ff_b2, n3_g, n3_b, (float*)d_out);
}